// Round 2
// baseline (289.810 us; speedup 1.0000x reference)
//
#include <hip/hip_runtime.h>
#include <hip/hip_bf16.h>

#define N0 300000
#define N1 60000
#define N2 6000
#define E1 1200000
#define E2 300000
#define D 128
#define DO 64

typedef __attribute__((ext_vector_type(8))) short bfrag8;
typedef __attribute__((ext_vector_type(4))) float f32x4;

#define WL_CAP 32768
#define UC_CAP 256

__device__ __forceinline__ float bf2f(unsigned short u) {
    union { unsigned int i; float f; } c; c.i = ((unsigned int)u) << 16; return c.f;
}
__device__ __forceinline__ unsigned short f2bf(float f) {
    return __bfloat16_as_ushort(__float2bfloat16(f));
}

// ---- layer 1 init: h (pre-BN, bf16) from history gather or self-loop+bias;
//      fused batch-stats accumulation ----
__global__ void __launch_bounds__(256) k_init_h(
        const float* __restrict__ x, const int* __restrict__ hmap,
        const float* __restrict__ hist, const float* __restrict__ Wself1,
        const float* __restrict__ b1, unsigned short* __restrict__ hb,
        float* __restrict__ stats, int* __restrict__ nuc,
        int* __restrict__ uc_slot, int* __restrict__ uc_node,
        float* __restrict__ hfix) {
    __shared__ float ls1[1024], ls2[1024];
    int tid = threadIdx.x;
    int lane = tid & 63;
    int q = tid & 31;                       // fixed per thread (stride % 32 == 0)
    float a1[4] = {0.f, 0.f, 0.f, 0.f}, a2[4] = {0.f, 0.f, 0.f, 0.f};
    int stride = gridDim.x * blockDim.x;    // multiple of 32
    for (int idx = blockIdx.x * blockDim.x + tid; idx < N1 * 32; idx += stride) {
        int node = idx >> 5;
        int m = hmap[node];
        float v[4];
        if (m >= 0) {
            float4 hv = ((const float4*)hist)[m * 32 + q];
            v[0] = hv.x; v[1] = hv.y; v[2] = hv.z; v[3] = hv.w;
        } else {
            int slot = -1;
            if (q == 0) {
                slot = atomicAdd(nuc, 1);
                if (slot < UC_CAP) { uc_slot[node] = slot; uc_node[slot] = node; }
            }
            slot = __shfl(slot, lane & 32, 64);
#pragma unroll
            for (int j = 0; j < 4; j++) v[j] = b1[q * 4 + j];
            for (int k = 0; k < D; k++) {
                float xv = x[(size_t)node * D + k];
#pragma unroll
                for (int j = 0; j < 4; j++) v[j] += xv * Wself1[k * D + q * 4 + j];
            }
            if (slot >= 0 && slot < UC_CAP) {
#pragma unroll
                for (int j = 0; j < 4; j++) hfix[slot * D + q * 4 + j] = v[j];
            }
        }
#pragma unroll
        for (int j = 0; j < 4; j++) { a1[j] += v[j]; a2[j] += v[j] * v[j]; }
        union { unsigned short b[4]; uint2 u; } o;
#pragma unroll
        for (int j = 0; j < 4; j++) o.b[j] = f2bf(v[j]);
        *(uint2*)(hb + (size_t)idx * 4) = o.u;
    }
#pragma unroll
    for (int j = 0; j < 4; j++) { ls1[tid * 4 + j] = a1[j]; ls2[tid * 4 + j] = a2[j]; }
    __syncthreads();
    if (tid < 32) {
#pragma unroll
        for (int j = 0; j < 4; j++) {
            float s = 0.f, ss = 0.f;
#pragma unroll
            for (int i = 0; i < 8; i++) { s += ls1[(tid + 32 * i) * 4 + j]; ss += ls2[(tid + 32 * i) * 4 + j]; }
            atomicAdd(&stats[tid * 4 + j], s);
            atomicAdd(&stats[128 + tid * 4 + j], ss);
        }
    }
}

// ---- find layer-1 edges whose dst has no history (rare) ----
__global__ void k_scan(const int* __restrict__ dst1, const int* __restrict__ hmap,
                       int* __restrict__ cnt, int* __restrict__ list) {
    int e = blockIdx.x * blockDim.x + threadIdx.x;
    if (e >= E1) return;
    if (hmap[dst1[e]] < 0) {
        int i = atomicAdd(cnt, 1);
        if (i < WL_CAP) list[i] = e;
    }
}

// ---- worklist edges: msg = W1[et]^T x[src] added into hfix (f32), with
//      telescoping stats fixup ----
__global__ void k_wl(const float* __restrict__ x, const int* __restrict__ src1,
                     const int* __restrict__ dst1, const int* __restrict__ et1,
                     const float* __restrict__ W1, const int* __restrict__ cnt,
                     const int* __restrict__ list, const int* __restrict__ uc_slot,
                     float* __restrict__ hfix, float* __restrict__ stats) {
    int c = threadIdx.x;  // 128
    int n = *cnt; if (n > WL_CAP) n = WL_CAP;
    for (int i = blockIdx.x; i < n; i += gridDim.x) {
        int e = list[i];
        int s = src1[e], d = dst1[e], t = et1[e];
        int slot = uc_slot[d];
        if (slot < 0 || slot >= UC_CAP) continue;
        float acc = 0.f;
        for (int k = 0; k < D; k++) acc += x[(size_t)s * D + k] * W1[(t * D + k) * D + c];
        float old = atomicAdd(&hfix[slot * D + c], acc);
        atomicAdd(&stats[c], acc);
        atomicAdd(&stats[128 + c], 2.f * old * acc + acc * acc);
    }
}

// ---- BN params from stats ----
__global__ void k_params(const float* __restrict__ stats, const float* __restrict__ gamma,
                         const float* __restrict__ beta, float* __restrict__ params) {
    int c = threadIdx.x;  // 128
    float mean = stats[c] / (float)N1;
    float var = stats[128 + c] / (float)N1 - mean * mean;
    float sc = gamma[c] * rsqrtf(var + 1e-5f);
    params[c] = sc;
    params[128 + c] = beta[c] - mean * sc;
}

// ---- apply BN + relu in place on bf16 h ----
__global__ void k_hb(unsigned short* __restrict__ hb, const float* __restrict__ params) {
    int idx = blockIdx.x * blockDim.x + threadIdx.x;  // over N1*16 chunks of 8
    if (idx >= N1 * 16) return;
    int c0 = (idx & 15) * 8;
    uint4 v = ((const uint4*)hb)[idx];
    unsigned int w[4] = {v.x, v.y, v.z, v.w};
    unsigned int r[4];
#pragma unroll
    for (int p = 0; p < 4; p++) {
        float f0 = bf2f((unsigned short)(w[p] & 0xffff));
        float f1 = bf2f((unsigned short)(w[p] >> 16));
        int c = c0 + p * 2;
        f0 = fmaxf(f0 * params[c] + params[128 + c], 0.f);
        f1 = fmaxf(f1 * params[c + 1] + params[128 + c + 1], 0.f);
        r[p] = (unsigned int)f2bf(f0) | ((unsigned int)f2bf(f1) << 16);
    }
    uint4 o; o.x = r[0]; o.y = r[1]; o.z = r[2]; o.w = r[3];
    ((uint4*)hb)[idx] = o;
}

// ---- exact BN+relu for the rare uncached nodes (overwrite) ----
__global__ void k_finish_uc(const int* __restrict__ nuc, const int* __restrict__ uc_node,
                            const float* __restrict__ hfix, const float* __restrict__ params,
                            unsigned short* __restrict__ hb) {
    int n = *nuc; if (n > UC_CAP) n = UC_CAP;
    int c = threadIdx.x;  // 128
    for (int slot = blockIdx.x; slot < n; slot += gridDim.x) {
        int node = uc_node[slot];
        float v = hfix[slot * D + c];
        v = fmaxf(v * params[c] + params[128 + c], 0.f);
        hb[(size_t)node * D + c] = f2bf(v);
    }
}

// ---- pre-swizzle B fragments for MFMA: 5 matrices (W2[0..3], Wself2) ----
__global__ void k_bfrag(const float* __restrict__ W2, const float* __restrict__ Wself2,
                        unsigned short* __restrict__ BF) {
    int idx = blockIdx.x * blockDim.x + threadIdx.x;  // 5*16*64*8 = 40960
    if (idx >= 40960) return;
    int j = idx & 7, lane = (idx >> 3) & 63, sub = (idx >> 9) & 15, g = idx >> 13;
    int kt = sub >> 2, ct = sub & 3;
    int k = kt * 32 + (lane >> 4) * 8 + j;
    int col = ct * 16 + (lane & 15);
    float v = (g < 4) ? W2[(g * D + k) * DO + col] : Wself2[k * DO + col];
    BF[idx] = f2bf(v);
}

// ---- Z[g] = hb @ B[g] for all 5 g in one pass (A loaded once) ----
__global__ void __launch_bounds__(256) k_gemm(const unsigned short* __restrict__ hb,
                                              const unsigned short* __restrict__ BF,
                                              unsigned short* __restrict__ Z) {
    int row0 = blockIdx.x * 64;
    int wave = threadIdx.x >> 6, lane = threadIdx.x & 63;
    int r = row0 + wave * 16 + (lane & 15);
    int rl = (r < N1) ? r : N1 - 1;
    int kb = (lane >> 4) * 8;
    bool doSelf = (row0 < N2);
    f32x4 acc[5][4] = {};
#pragma unroll
    for (int kt = 0; kt < 4; kt++) {
        bfrag8 a = *reinterpret_cast<const bfrag8*>(hb + (size_t)rl * D + kt * 32 + kb);
#pragma unroll
        for (int g = 0; g < 5; g++) {
            if (g == 4 && !doSelf) continue;
#pragma unroll
            for (int ct = 0; ct < 4; ct++) {
                bfrag8 b = *reinterpret_cast<const bfrag8*>(BF + ((((g * 4 + kt) * 4 + ct) * 64 + lane) * 8));
                acc[g][ct] = __builtin_amdgcn_mfma_f32_16x16x32_bf16(a, b, acc[g][ct], 0, 0, 0);
            }
        }
    }
    int srow = row0 + wave * 16 + (lane >> 4) * 4;
    int col = lane & 15;
#pragma unroll
    for (int g = 0; g < 5; g++) {
        int rows = (g == 4) ? N2 : N1;
        if (g == 4 && !doSelf) continue;
#pragma unroll
        for (int ct = 0; ct < 4; ct++) {
#pragma unroll
            for (int i = 0; i < 4; i++) {
                int rr = srow + i;
                if (rr < rows) Z[((size_t)g * N1 + rr) * DO + ct * 16 + col] = f2bf(acc[g][ct][i]);
            }
        }
    }
}

// ---- CSR build over layer-2 edges ----
__global__ void k_ehist(const int* __restrict__ dst2, int* __restrict__ ehist) {
    int e = blockIdx.x * blockDim.x + threadIdx.x;
    if (e >= E2) return;
    atomicAdd(&ehist[dst2[e]], 1);
}

__global__ void k_escan(const int* __restrict__ ehist, int* __restrict__ rs,
                        int* __restrict__ rs2) {
    __shared__ int part[256];
    int t = threadIdx.x;
    int lo = t * 24, hi = lo + 24; if (hi > N2) hi = N2;
    int s = 0;
    for (int i = lo; i < hi && i < N2; i++) s += ehist[i];
    part[t] = s;
    __syncthreads();
    if (t == 0) {
        int a = 0;
        for (int i = 0; i < 256; i++) { int v = part[i]; part[i] = a; a += v; }
        rs[N2] = a;
    }
    __syncthreads();
    int a = part[t];
    for (int i = lo; i < hi && i < N2; i++) {
        rs[i] = a; rs2[i] = a; a += ehist[i];
    }
}

__global__ void k_escatter(const int* __restrict__ src2, const int* __restrict__ dst2,
                           const int* __restrict__ et2, int* __restrict__ rs2,
                           int* __restrict__ epay) {
    int e = blockIdx.x * blockDim.x + threadIdx.x;
    if (e >= E2) return;
    int d = dst2[e];
    int pos = atomicAdd(&rs2[d], 1);
    epay[pos] = src2[e] | (et2[e] << 16);
}

// ---- fused: out[d] = logsoftmax(b2 + Zself[d] + sum_e Z[et][src]) ----
__global__ void __launch_bounds__(256) k_out(const float* __restrict__ b2,
                                             const unsigned short* __restrict__ Z,
                                             const int* __restrict__ rs,
                                             const int* __restrict__ epay,
                                             float* __restrict__ out) {
    int wave = threadIdx.x >> 6, o = threadIdx.x & 63;
    int d = blockIdx.x * 4 + wave;
    if (d >= N2) return;
    float acc = b2[o] + bf2f(Z[((size_t)4 * N1 + d) * DO + o]);
    int j0 = rs[d], j1 = rs[d + 1];
    for (int j = j0; j < j1; j++) {
        int p = epay[j];
        int s = p & 0xffff, t = p >> 16;
        acc += bf2f(Z[((size_t)t * N1 + s) * DO + o]);
    }
    float m = acc;
#pragma unroll
    for (int sh = 32; sh; sh >>= 1) m = fmaxf(m, __shfl_xor(m, sh, 64));
    float ex = expf(acc - m);
    float sum = ex;
#pragma unroll
    for (int sh = 32; sh; sh >>= 1) sum += __shfl_xor(sum, sh, 64);
    out[(size_t)d * DO + o] = acc - m - logf(sum);
}

extern "C" void kernel_launch(void* const* d_in, const int* in_sizes, int n_in,
                              void* d_out, int out_size, void* d_ws, size_t ws_size,
                              hipStream_t stream) {
    const float* x      = (const float*)d_in[0];
    const int* src1     = (const int*)d_in[1];
    const int* dst1     = (const int*)d_in[2];
    const int* et1      = (const int*)d_in[3];
    const int* src2     = (const int*)d_in[4];
    const int* dst2     = (const int*)d_in[5];
    const int* et2      = (const int*)d_in[6];
    const int* hmap     = (const int*)d_in[7];
    const float* hist   = (const float*)d_in[8];
    const float* W1     = (const float*)d_in[9];
    const float* Wself1 = (const float*)d_in[10];
    const float* b1     = (const float*)d_in[11];
    const float* gamma  = (const float*)d_in[12];
    const float* beta   = (const float*)d_in[13];
    const float* W2     = (const float*)d_in[14];
    const float* Wself2 = (const float*)d_in[15];
    const float* b2     = (const float*)d_in[16];
    float* out = (float*)d_out;

    char* ws = (char*)d_ws;
    unsigned short* hb  = (unsigned short*)(ws);              // 15,360,000
    unsigned short* Z   = (unsigned short*)(ws + 15360000);   // 38,400,000
    unsigned short* BF  = (unsigned short*)(ws + 53760000);   //     81,920
    float* hfix         = (float*)(ws + 53841920);            //    131,072
    int* uc_node        = (int*)(ws + 53972992);              //      1,024
    int* uc_slot        = (int*)(ws + 53974016);              //    240,000
    int* epay           = (int*)(ws + 54214016);              //  1,200,000
    int* rs             = (int*)(ws + 55414016);              //     24,016
    int* rs2            = (int*)(ws + 55438032);              //     24,000
    float* stats        = (float*)(ws + 55462048);            //      1,024
    int* cnt            = (int*)(ws + 55463072);              //          4
    int* nuc            = (int*)(ws + 55463076);              //          4
    int* ehist          = (int*)(ws + 55463088);              //     24,000
    int* list           = (int*)(ws + 55487104);              //    131,072
    float* params       = (float*)(ws + 55618176);            //      1,024

    // zero: stats + cnt + nuc + pad + ehist (contiguous region)
    hipMemsetAsync(stats, 0, 1024 + 16 + 24000, stream);

    k_init_h<<<1024, 256, 0, stream>>>(x, hmap, hist, Wself1, b1, hb,
                                       stats, nuc, uc_slot, uc_node, hfix);
    k_scan<<<(E1 + 255) / 256, 256, 0, stream>>>(dst1, hmap, cnt, list);
    k_wl<<<256, 128, 0, stream>>>(x, src1, dst1, et1, W1, cnt, list, uc_slot, hfix, stats);
    k_params<<<1, 128, 0, stream>>>(stats, gamma, beta, params);
    k_hb<<<(N1 * 16 + 255) / 256, 256, 0, stream>>>(hb, params);
    k_finish_uc<<<8, 128, 0, stream>>>(nuc, uc_node, hfix, params, hb);
    k_bfrag<<<160, 256, 0, stream>>>(W2, Wself2, BF);
    k_ehist<<<(E2 + 255) / 256, 256, 0, stream>>>(dst2, ehist);
    k_escan<<<1, 256, 0, stream>>>(ehist, rs, rs2);
    k_escatter<<<(E2 + 255) / 256, 256, 0, stream>>>(src2, dst2, et2, rs2, epay);
    k_gemm<<<(N1 + 63) / 64, 256, 0, stream>>>(hb, BF, Z);
    k_out<<<(N2 + 3) / 4, 256, 0, stream>>>(b2, Z, rs, epay, out);
}

// Round 3
// 130.607 us; speedup vs baseline: 2.2189x; 2.2189x over previous
//
#include <hip/hip_runtime.h>
#include <hip/hip_bf16.h>

#define N0 300000
#define N1 60000
#define N2 6000
#define E1 1200000
#define E2 300000
#define D 128
#define DO 64

typedef __attribute__((ext_vector_type(8))) short bfrag8;
typedef __attribute__((ext_vector_type(4))) float f32x4;

#define WL_CAP 32768
#define UC_CAP 256

__device__ __forceinline__ float bf2f(unsigned int u) {
    union { unsigned int i; float f; } c; c.i = u << 16; return c.f;
}
__device__ __forceinline__ unsigned short f2bf(float f) {
    return __bfloat16_as_ushort(__float2bfloat16(f));
}

// ---- layer 1 init: hb (pre-BN, bf16) = history gather, or self-loop+bias for
//      the rare uncached nodes (also recorded into hfix slots). Full-throw. ----
__global__ void __launch_bounds__(256) k_init_h(
        const float* __restrict__ x, const int* __restrict__ hmap,
        const float* __restrict__ hist, const float* __restrict__ Wself1,
        const float* __restrict__ b1, unsigned short* __restrict__ hb,
        int* __restrict__ nuc, int* __restrict__ uc_slot,
        int* __restrict__ uc_node, float* __restrict__ hfix) {
    int idx = blockIdx.x * 256 + threadIdx.x;   // exactly N1*32 threads
    int node = idx >> 5, q = idx & 31;
    int lane = threadIdx.x & 63;
    int m = hmap[node];
    float v[4];
    if (m >= 0) {
        float4 hv = ((const float4*)hist)[m * 32 + q];
        v[0] = hv.x; v[1] = hv.y; v[2] = hv.z; v[3] = hv.w;
    } else {
        int slot = -1;
        if (q == 0) {
            slot = atomicAdd(nuc, 1);
            if (slot < UC_CAP) { uc_slot[node] = slot; uc_node[slot] = node; }
        }
        slot = __shfl(slot, lane & 32, 64);
#pragma unroll
        for (int j = 0; j < 4; j++) v[j] = b1[q * 4 + j];
        for (int k = 0; k < D; k++) {
            float xv = x[(size_t)node * D + k];
#pragma unroll
            for (int j = 0; j < 4; j++) v[j] += xv * Wself1[k * D + q * 4 + j];
        }
        if (slot >= 0 && slot < UC_CAP) {
#pragma unroll
            for (int j = 0; j < 4; j++) hfix[slot * D + q * 4 + j] = v[j];
        }
    }
    union { unsigned short b[4]; uint2 u; } o;
#pragma unroll
    for (int j = 0; j < 4; j++) o.b[j] = f2bf(v[j]);
    *(uint2*)(hb + (size_t)idx * 4) = o.u;
}

// ---- fused: layer-1 worklist scan + layer-2 dst histogram ----
__global__ void k_scan_ehist(const int* __restrict__ dst1, const int* __restrict__ hmap,
                             int* __restrict__ cnt, int* __restrict__ list,
                             const int* __restrict__ dst2, int* __restrict__ ehist) {
    int e = blockIdx.x * blockDim.x + threadIdx.x;
    if (e < E2) atomicAdd(&ehist[dst2[e]], 1);
    if (e >= E1) return;
    if (hmap[dst1[e]] < 0) {
        int i = atomicAdd(cnt, 1);
        if (i < WL_CAP) list[i] = e;
    }
}

// ---- BN batch stats: streaming pass over hb, non-atomic two-level reduce ----
__global__ void __launch_bounds__(256) k_stats(const unsigned short* __restrict__ hb,
                                               float* __restrict__ psum) {
    __shared__ float ls1[2048], ls2[2048];
    int tid = threadIdx.x;
    float s[8] = {0,0,0,0,0,0,0,0}, ss[8] = {0,0,0,0,0,0,0,0};
    int stride = gridDim.x * 256;               // multiple of 16
    for (int idx = blockIdx.x * 256 + tid; idx < N1 * 16; idx += stride) {
        uint4 w = ((const uint4*)hb)[idx];
        unsigned int u[4] = {w.x, w.y, w.z, w.w};
#pragma unroll
        for (int p = 0; p < 4; p++) {
            float f0 = bf2f(u[p] & 0xffff);
            float f1 = bf2f(u[p] >> 16);
            s[2*p] += f0; ss[2*p] += f0 * f0;
            s[2*p+1] += f1; ss[2*p+1] += f1 * f1;
        }
    }
#pragma unroll
    for (int k = 0; k < 8; k++) { ls1[tid * 8 + k] = s[k]; ls2[tid * 8 + k] = ss[k]; }
    __syncthreads();
    if (tid < 128) {
        int sl = tid >> 3, el = tid & 7;        // col c = tid
        float S = 0.f, SS = 0.f;
#pragma unroll
        for (int g = 0; g < 16; g++) {
            int src = (sl + 16 * g) * 8 + el;
            S += ls1[src]; SS += ls2[src];
        }
        psum[blockIdx.x * 256 + tid] = S;
        psum[blockIdx.x * 256 + 128 + tid] = SS;
    }
}

// ---- worklist edges: msg = W1[et]^T x[src] into hfix; telescoping stats fix ----
__global__ void k_wl(const float* __restrict__ x, const int* __restrict__ src1,
                     const int* __restrict__ dst1, const int* __restrict__ et1,
                     const float* __restrict__ W1, const int* __restrict__ cnt,
                     const int* __restrict__ list, const int* __restrict__ uc_slot,
                     float* __restrict__ hfix, float* __restrict__ statsfix) {
    int c = threadIdx.x;  // 128
    int n = *cnt; if (n > WL_CAP) n = WL_CAP;
    for (int i = blockIdx.x; i < n; i += gridDim.x) {
        int e = list[i];
        int s = src1[e], d = dst1[e], t = et1[e];
        int slot = uc_slot[d];
        if (slot < 0 || slot >= UC_CAP) continue;
        float acc = 0.f;
        for (int k = 0; k < D; k++) acc += x[(size_t)s * D + k] * W1[(t * D + k) * D + c];
        float old = atomicAdd(&hfix[slot * D + c], acc);
        atomicAdd(&statsfix[c], acc);
        atomicAdd(&statsfix[128 + c], 2.f * old * acc + acc * acc);
    }
}

// ---- block 0: CSR scan over ehist; block 1: BN params from psum+statsfix ----
__global__ void k_escan_params(const int* __restrict__ ehist, int* __restrict__ rs,
                               int* __restrict__ rs2, const float* __restrict__ psum,
                               const float* __restrict__ statsfix,
                               const float* __restrict__ gamma,
                               const float* __restrict__ beta,
                               float* __restrict__ params) {
    if (blockIdx.x == 1) {
        int c = threadIdx.x;
        if (c < 128) {
            float S = statsfix[c], SS = statsfix[128 + c];
            for (int b = 0; b < 256; b++) {
                S += psum[b * 256 + c];
                SS += psum[b * 256 + 128 + c];
            }
            float mean = S / (float)N1;
            float var = SS / (float)N1 - mean * mean;
            float sc = gamma[c] * rsqrtf(var + 1e-5f);
            params[c] = sc;
            params[128 + c] = beta[c] - mean * sc;
        }
        return;
    }
    __shared__ int part[256];
    int t = threadIdx.x;
    int lo = t * 24, hi = lo + 24; if (hi > N2) hi = N2;
    int s = 0;
    for (int i = lo; i < hi && i < N2; i++) s += ehist[i];
    part[t] = s;
    __syncthreads();
    if (t == 0) {
        int a = 0;
        for (int i = 0; i < 256; i++) { int v = part[i]; part[i] = a; a += v; }
        rs[N2] = a;
    }
    __syncthreads();
    int a = part[t];
    for (int i = lo; i < hi && i < N2; i++) {
        rs[i] = a; rs2[i] = a; a += ehist[i];
    }
}

// ---- apply BN + relu in place on bf16 hb ----
__global__ void k_hb(unsigned short* __restrict__ hb, const float* __restrict__ params) {
    int idx = blockIdx.x * blockDim.x + threadIdx.x;  // exactly N1*16
    int c0 = (idx & 15) * 8;
    uint4 v = ((const uint4*)hb)[idx];
    unsigned int w[4] = {v.x, v.y, v.z, v.w};
    unsigned int r[4];
#pragma unroll
    for (int p = 0; p < 4; p++) {
        float f0 = bf2f(w[p] & 0xffff);
        float f1 = bf2f(w[p] >> 16);
        int c = c0 + p * 2;
        f0 = fmaxf(f0 * params[c] + params[128 + c], 0.f);
        f1 = fmaxf(f1 * params[c + 1] + params[128 + c + 1], 0.f);
        r[p] = (unsigned int)f2bf(f0) | ((unsigned int)f2bf(f1) << 16);
    }
    uint4 o; o.x = r[0]; o.y = r[1]; o.z = r[2]; o.w = r[3];
    ((uint4*)hb)[idx] = o;
}

// ---- exact BN+relu for the rare uncached nodes (overwrite) ----
__global__ void k_finish_uc(const int* __restrict__ nuc, const int* __restrict__ uc_node,
                            const float* __restrict__ hfix, const float* __restrict__ params,
                            unsigned short* __restrict__ hb) {
    int n = *nuc; if (n > UC_CAP) n = UC_CAP;
    int c = threadIdx.x;  // 128
    for (int slot = blockIdx.x; slot < n; slot += gridDim.x) {
        int node = uc_node[slot];
        float v = hfix[slot * D + c];
        v = fmaxf(v * params[c] + params[128 + c], 0.f);
        hb[(size_t)node * D + c] = f2bf(v);
    }
}

// ---- pre-swizzle B fragments for MFMA: 5 matrices (W2[0..3], Wself2) ----
__global__ void k_bfrag(const float* __restrict__ W2, const float* __restrict__ Wself2,
                        unsigned short* __restrict__ BF) {
    int idx = blockIdx.x * blockDim.x + threadIdx.x;  // 5*16*64*8 = 40960
    if (idx >= 40960) return;
    int j = idx & 7, lane = (idx >> 3) & 63, sub = (idx >> 9) & 15, g = idx >> 13;
    int kt = sub >> 2, ct = sub & 3;
    int k = kt * 32 + (lane >> 4) * 8 + j;
    int col = ct * 16 + (lane & 15);
    float v = (g < 4) ? W2[(g * D + k) * DO + col] : Wself2[k * DO + col];
    BF[idx] = f2bf(v);
}

// ---- CSR scatter of layer-2 edges ----
__global__ void k_escatter(const int* __restrict__ src2, const int* __restrict__ dst2,
                           const int* __restrict__ et2, int* __restrict__ rs2,
                           int* __restrict__ epay) {
    int e = blockIdx.x * blockDim.x + threadIdx.x;
    if (e >= E2) return;
    int d = dst2[e];
    int pos = atomicAdd(&rs2[d], 1);
    epay[pos] = src2[e] | (et2[e] << 16);
}

// ---- aggregate-then-transform: per-dst per-relation sum of hb[src] rows ----
#define AGG_ACC(P, V) { \
    int t_ = (P) >> 16; \
    float f0_ = bf2f((V) & 0xffff), f1_ = bf2f((V) >> 16); \
    acc[0][0] += (t_ == 0) ? f0_ : 0.f; acc[0][1] += (t_ == 0) ? f1_ : 0.f; \
    acc[1][0] += (t_ == 1) ? f0_ : 0.f; acc[1][1] += (t_ == 1) ? f1_ : 0.f; \
    acc[2][0] += (t_ == 2) ? f0_ : 0.f; acc[2][1] += (t_ == 2) ? f1_ : 0.f; \
    acc[3][0] += (t_ == 3) ? f0_ : 0.f; acc[3][1] += (t_ == 3) ? f1_ : 0.f; }

__global__ void __launch_bounds__(256) k_agg(const unsigned int* __restrict__ hbu,
                                             const int* __restrict__ rs,
                                             const int* __restrict__ epay,
                                             unsigned int* __restrict__ aggbu) {
    int wave = threadIdx.x >> 6, lane = threadIdx.x & 63;
    int d = blockIdx.x * 4 + wave;
    if (d >= N2) return;
    float acc[4][2] = {};
    int j0 = rs[d], j1 = rs[d + 1];
    int j = j0;
    for (; j + 4 <= j1; j += 4) {
        int p0 = epay[j], p1 = epay[j + 1], p2 = epay[j + 2], p3 = epay[j + 3];
        unsigned int v0 = hbu[(size_t)(p0 & 0xffff) * 64 + lane];
        unsigned int v1 = hbu[(size_t)(p1 & 0xffff) * 64 + lane];
        unsigned int v2 = hbu[(size_t)(p2 & 0xffff) * 64 + lane];
        unsigned int v3 = hbu[(size_t)(p3 & 0xffff) * 64 + lane];
        AGG_ACC(p0, v0); AGG_ACC(p1, v1); AGG_ACC(p2, v2); AGG_ACC(p3, v3);
    }
    for (; j < j1; j++) {
        int p = epay[j];
        unsigned int v = hbu[(size_t)(p & 0xffff) * 64 + lane];
        AGG_ACC(p, v);
    }
#pragma unroll
    for (int t = 0; t < 4; t++) {
        unsigned int o = (unsigned int)f2bf(acc[t][0]) | ((unsigned int)f2bf(acc[t][1]) << 16);
        aggbu[((size_t)t * N2 + d) * 64 + lane] = o;
    }
}

// ---- out[d] = logsoftmax(b2 + hb[d]@Wself2 + sum_t agg[t][d]@W2[t]) ----
__global__ void __launch_bounds__(256) k_gemm2(const unsigned short* __restrict__ aggb,
                                               const unsigned short* __restrict__ hb,
                                               const unsigned short* __restrict__ BF,
                                               const float* __restrict__ b2,
                                               float* __restrict__ out) {
    int row0 = blockIdx.x * 64;
    int wave = threadIdx.x >> 6, lane = threadIdx.x & 63;
    int r = row0 + wave * 16 + (lane & 15);
    int rl = (r < N2) ? r : N2 - 1;
    int kb = (lane >> 4) * 8;
    f32x4 acc[4] = {};
#pragma unroll
    for (int kt = 0; kt < 4; kt++) {
#pragma unroll
        for (int g = 0; g < 5; g++) {
            const unsigned short* ap = (g < 4)
                ? aggb + ((size_t)(g * N2 + rl) * D + kt * 32 + kb)
                : hb + ((size_t)rl * D + kt * 32 + kb);
            bfrag8 a = *reinterpret_cast<const bfrag8*>(ap);
#pragma unroll
            for (int ct = 0; ct < 4; ct++) {
                bfrag8 b = *reinterpret_cast<const bfrag8*>(BF + ((((g * 4 + kt) * 4 + ct) * 64 + lane) * 8));
                acc[ct] = __builtin_amdgcn_mfma_f32_16x16x32_bf16(a, b, acc[ct], 0, 0, 0);
            }
        }
    }
    float bb[4];
#pragma unroll
    for (int ct = 0; ct < 4; ct++) bb[ct] = b2[ct * 16 + (lane & 15)];
    int srow = row0 + wave * 16 + (lane >> 4) * 4;
#pragma unroll
    for (int i = 0; i < 4; i++) {
        float v[4];
#pragma unroll
        for (int ct = 0; ct < 4; ct++) v[ct] = acc[ct][i] + bb[ct];
        float m = fmaxf(fmaxf(v[0], v[1]), fmaxf(v[2], v[3]));
#pragma unroll
        for (int sh = 1; sh <= 8; sh <<= 1) m = fmaxf(m, __shfl_xor(m, sh, 64));
        float s = 0.f;
#pragma unroll
        for (int ct = 0; ct < 4; ct++) s += expf(v[ct] - m);
#pragma unroll
        for (int sh = 1; sh <= 8; sh <<= 1) s += __shfl_xor(s, sh, 64);
        float lg = m + logf(s);
        int rr = srow + i;
        if (rr < N2) {
#pragma unroll
            for (int ct = 0; ct < 4; ct++)
                out[(size_t)rr * DO + ct * 16 + (lane & 15)] = v[ct] - lg;
        }
    }
}

extern "C" void kernel_launch(void* const* d_in, const int* in_sizes, int n_in,
                              void* d_out, int out_size, void* d_ws, size_t ws_size,
                              hipStream_t stream) {
    const float* x      = (const float*)d_in[0];
    const int* src1     = (const int*)d_in[1];
    const int* dst1     = (const int*)d_in[2];
    const int* et1      = (const int*)d_in[3];
    const int* src2     = (const int*)d_in[4];
    const int* dst2     = (const int*)d_in[5];
    const int* et2      = (const int*)d_in[6];
    const int* hmap     = (const int*)d_in[7];
    const float* hist   = (const float*)d_in[8];
    const float* W1     = (const float*)d_in[9];
    const float* Wself1 = (const float*)d_in[10];
    const float* b1     = (const float*)d_in[11];
    const float* gamma  = (const float*)d_in[12];
    const float* beta   = (const float*)d_in[13];
    const float* W2     = (const float*)d_in[14];
    const float* Wself2 = (const float*)d_in[15];
    const float* b2     = (const float*)d_in[16];
    float* out = (float*)d_out;

    char* ws = (char*)d_ws;
    unsigned short* hb   = (unsigned short*)(ws);              // 15,360,000
    unsigned short* aggb = (unsigned short*)(ws + 15360000);   //  6,144,000
    unsigned short* BF   = (unsigned short*)(ws + 21504000);   //     81,920
    float* hfix          = (float*)(ws + 21585920);            //    131,072
    int* uc_node         = (int*)(ws + 21716992);              //      1,024
    int* uc_slot         = (int*)(ws + 21718016);              //    240,000
    int* epay            = (int*)(ws + 21958016);              //  1,200,000
    int* rs              = (int*)(ws + 23158016);              //     24,016
    int* rs2             = (int*)(ws + 23182032);              //     24,000
    float* psum          = (float*)(ws + 23206032);            //    262,144
    float* statsfix      = (float*)(ws + 23468176);            //      1,024
    int* cnt             = (int*)(ws + 23469200);              //          4
    int* nuc             = (int*)(ws + 23469204);              //          4
    int* ehist           = (int*)(ws + 23469216);              //     24,000
    int* list            = (int*)(ws + 23493216);              //    131,072
    float* params        = (float*)(ws + 23624288);            //      1,024

    // zero statsfix + cnt + nuc + pad + ehist in one shot
    hipMemsetAsync(statsfix, 0, 25040, stream);

    k_init_h<<<7500, 256, 0, stream>>>(x, hmap, hist, Wself1, b1, hb,
                                       nuc, uc_slot, uc_node, hfix);
    k_scan_ehist<<<(E1 + 255) / 256, 256, 0, stream>>>(dst1, hmap, cnt, list, dst2, ehist);
    k_stats<<<256, 256, 0, stream>>>(hb, psum);
    k_wl<<<256, 128, 0, stream>>>(x, src1, dst1, et1, W1, cnt, list, uc_slot, hfix, statsfix);
    k_escan_params<<<2, 256, 0, stream>>>(ehist, rs, rs2, psum, statsfix, gamma, beta, params);
    k_hb<<<3750, 256, 0, stream>>>(hb, params);
    k_finish_uc<<<8, 128, 0, stream>>>(nuc, uc_node, hfix, params, hb);
    k_bfrag<<<160, 256, 0, stream>>>(W2, Wself2, BF);
    k_escatter<<<(E2 + 255) / 256, 256, 0, stream>>>(src2, dst2, et2, rs2, epay);
    k_agg<<<1500, 256, 0, stream>>>((const unsigned int*)hb, rs, epay, (unsigned int*)aggb);
    k_gemm2<<<94, 256, 0, stream>>>(aggb, hb, BF, b2, out);
}